// Round 8
// baseline (126.981 us; speedup 1.0000x reference)
//
#include <hip/hip_runtime.h>
#include <hip/hip_bf16.h>
#include <stdint.h>

typedef __attribute__((ext_vector_type(8))) short bf16x8;
typedef __attribute__((ext_vector_type(4))) float f32x4;

#define T_TOKENS 8192
#define DIM 1024
#define ODIM 1024
#define NEXP 8

__device__ __forceinline__ unsigned short f2bf(float f) {
  unsigned u = __float_as_uint(f);
  u = (u + 0x7FFFu + ((u >> 16) & 1u)) >> 16;
  return (unsigned short)u;
}
__device__ __forceinline__ float bf2f(unsigned short h) {
  return __uint_as_float(((unsigned)h) << 16);
}

// ---------------- router: fp32 logits, top-2, weights; emits x in bf16. NO atomics. ----------------
__global__ __launch_bounds__(256) void router_kernel(
    const float* __restrict__ x, const float* __restrict__ gw, const float* __restrict__ gb,
    float* __restrict__ logits_out, unsigned short* __restrict__ x_bf,
    int* __restrict__ tk_e, float* __restrict__ tk_w) {
  int wave = threadIdx.x >> 6, lane = threadIdx.x & 63;
  int t = blockIdx.x * 4 + wave;
  float acc[NEXP];
#pragma unroll
  for (int e = 0; e < NEXP; ++e) acc[e] = 0.f;
  const float4* xr = (const float4*)(x + (size_t)t * DIM);
  ushort4* xw = (ushort4*)(x_bf + (size_t)t * DIM);
#pragma unroll
  for (int it = 0; it < 4; ++it) {
    int d4 = it * 64 + lane;
    float4 xv = xr[d4];
    ushort4 xb;
    xb.x = f2bf(xv.x); xb.y = f2bf(xv.y); xb.z = f2bf(xv.z); xb.w = f2bf(xv.w);
    xw[d4] = xb;
#pragma unroll
    for (int e = 0; e < NEXP; ++e) {
      float4 gv = ((const float4*)(gw + e * DIM))[d4];
      acc[e] += xv.x * gv.x + xv.y * gv.y + xv.z * gv.z + xv.w * gv.w;
    }
  }
#pragma unroll
  for (int off = 32; off; off >>= 1)
#pragma unroll
    for (int e = 0; e < NEXP; ++e) acc[e] += __shfl_xor(acc[e], off);
  if (lane == 0) {
#pragma unroll
    for (int e = 0; e < NEXP; ++e) acc[e] += gb[e];
    float4 lo = make_float4(acc[0], acc[1], acc[2], acc[3]);
    float4 hi = make_float4(acc[4], acc[5], acc[6], acc[7]);
    float4* lp = (float4*)(logits_out + (size_t)t * NEXP);
    lp[0] = lo; lp[1] = hi;
    int e0 = 0; float l0 = acc[0];
#pragma unroll
    for (int e = 1; e < NEXP; ++e) if (acc[e] > l0) { l0 = acc[e]; e0 = e; }
    int e1 = -1; float l1 = -1e30f;
#pragma unroll
    for (int e = 0; e < NEXP; ++e) if (e != e0 && acc[e] > l1) { l1 = acc[e]; e1 = e; }
    float r = expf(l1 - l0);          // p1/p0
    float w0 = 1.f / (1.f + r);
    float w1 = r * w0;
    tk_e[t * 2] = e0; tk_e[t * 2 + 1] = e1;
    tk_w[t * 2] = w0; tk_w[t * 2 + 1] = w1;
  }
}

// ---------------- fused: block 0 = counting sort + tile schedule; blocks 1..2048 = expert_w convert.
__global__ __launch_bounds__(1024) void sortconv_kernel(
    const float* __restrict__ ew, unsigned short* __restrict__ w_bf,
    const int* __restrict__ tk_e, const float* __restrict__ tk_w,
    int* __restrict__ offsets_g, int* __restrict__ row_token,
    float* __restrict__ row_weight, int* __restrict__ tk_pos,
    int* __restrict__ tiles_g, int* __restrict__ n_tiles_g) {
  if (blockIdx.x > 0) {
    int i = (blockIdx.x - 1) * 1024 + threadIdx.x;  // 2M float4s
    float4 v = ((const float4*)ew)[i];
    ushort4 o;
    o.x = f2bf(v.x); o.y = f2bf(v.y); o.z = f2bf(v.z); o.w = f2bf(v.w);
    ((ushort4*)w_bf)[i] = o;
    return;
  }
  int tid = threadIdx.x;
  int lane = tid & 63, wv = tid >> 6;  // 16 waves
  __shared__ int wavetot[16][NEXP];    // then reused as wave exclusive base
  __shared__ int offs_l[NEXP + 1];

  int pe[16];
  float tw[16];
  const int base = tid * 16;
#pragma unroll
  for (int i = 0; i < 4; ++i) {
    int4 v = ((const int4*)(tk_e + base))[i];
    pe[i * 4 + 0] = v.x; pe[i * 4 + 1] = v.y; pe[i * 4 + 2] = v.z; pe[i * 4 + 3] = v.w;
    float4 w = ((const float4*)(tk_w + base))[i];
    tw[i * 4 + 0] = w.x; tw[i * 4 + 1] = w.y; tw[i * 4 + 2] = w.z; tw[i * 4 + 3] = w.w;
  }
  int h[NEXP];
#pragma unroll
  for (int e = 0; e < NEXP; ++e) h[e] = 0;
#pragma unroll
  for (int i = 0; i < 16; ++i)
#pragma unroll
    for (int e = 0; e < NEXP; ++e) h[e] += (pe[i] == e);

  int incl[NEXP];
#pragma unroll
  for (int e = 0; e < NEXP; ++e) incl[e] = h[e];
#pragma unroll
  for (int off = 1; off < 64; off <<= 1) {
#pragma unroll
    for (int e = 0; e < NEXP; ++e) {
      int n = __shfl_up(incl[e], off);
      if (lane >= off) incl[e] += n;
    }
  }
  if (lane == 63)
#pragma unroll
    for (int e = 0; e < NEXP; ++e) wavetot[wv][e] = incl[e];
  __syncthreads();
  if (tid == 0) {
    int tot[NEXP];
#pragma unroll
    for (int e = 0; e < NEXP; ++e) tot[e] = 0;
    for (int w = 0; w < 16; ++w)
#pragma unroll
      for (int e = 0; e < NEXP; ++e) {
        int v = wavetot[w][e];
        wavetot[w][e] = tot[e];  // exclusive base per wave
        tot[e] += v;
      }
    int o = 0;
#pragma unroll
    for (int e = 0; e < NEXP; ++e) { offs_l[e] = o; o += tot[e]; }
    offs_l[NEXP] = o;
    for (int e = 0; e <= NEXP; ++e) offsets_g[e] = offs_l[e];
    // block schedule: expert-major, m-tile(128 rows) major, n-tile(256 cols) fast
    int nb = 0;
    for (int e = 0; e < NEXP; ++e) {
      int mt = (tot[e] + 127) >> 7;
      for (int m = 0; m < mt; ++m)
        for (int n = 0; n < 4; ++n) tiles_g[nb++] = e | (n << 4) | (m << 8);
    }
    n_tiles_g[0] = nb;
    n_tiles_g[1] = (nb + 7) >> 3;  // chunk size per XCD column
  }
  __syncthreads();

  int mybase[NEXP];
#pragma unroll
  for (int e = 0; e < NEXP; ++e) mybase[e] = offs_l[e] + wavetot[wv][e] + (incl[e] - h[e]);
  int run[NEXP];
#pragma unroll
  for (int e = 0; e < NEXP; ++e) run[e] = 0;
#pragma unroll
  for (int i = 0; i < 16; ++i) {
    int pos = 0;
#pragma unroll
    for (int e = 0; e < NEXP; ++e)
      if (pe[i] == e) { pos = mybase[e] + run[e]; run[e]++; }
    int pair = base + i;
    row_token[pos] = pair >> 1;
    row_weight[pos] = tw[i];
    tk_pos[pair] = pos;
  }
}

// ---------------- grouped GEMM: 128x256 tile, BK=32, dbuf 48KB LDS, 8 waves (2M x 4N, wave 64x64),
// 2 blocks/CU (launch_bounds 512,4) for cross-block latency cover; R4-style 1 barrier/K-tile.
#define GLOAD16(g, l)                                                                   \
  __builtin_amdgcn_global_load_lds((const __attribute__((address_space(1))) unsigned int*)(g), \
                                   (__attribute__((address_space(3))) unsigned int*)(l), 16, 0, 0)

__global__ __launch_bounds__(512, 4) void gemm_kernel(
    const unsigned short* __restrict__ x_bf, const unsigned short* __restrict__ w_bf,
    const int* __restrict__ row_token, const float* __restrict__ row_weight,
    const int* __restrict__ offsets, const int* __restrict__ tiles,
    const int* __restrict__ n_tiles, unsigned short* __restrict__ tmp) {
  int nb = n_tiles[0], cpx = n_tiles[1];
  int wg = blockIdx.x;
  int slot = wg >> 3;
  if (slot >= cpx) return;
  int idx = (wg & 7) * cpx + slot;   // chunked: XCD column gets contiguous schedule run
  if (idx >= nb) return;
  int s = tiles[idx];
  int e = s & 7;
  int n0 = ((s >> 4) & 3) << 8;
  int m0 = (s >> 8) << 7;
  int seg0 = offsets[e], segN = offsets[e + 1] - seg0;

  int tid = threadIdx.x;
  int lane = tid & 63, wave = tid >> 6;
  int wr = wave >> 2, wc = wave & 3;  // 2M x 4N wave grid; wave output 64x64

  // per buffer (24KB): A[128][32]bf16 @0 (8KB), B[256][32]bf16 @8192. Buffers @0, @24576.
  __shared__ __align__(16) char smem[49152];

  // ---- staging: per K-tile 3 gloads (1 A + 2 B), each 512thr x 16B. 64B rows,
  // chunk swizzle: chunk ^= (row>>1)&3 (conflict-free per 8-lane subgroup). ----
  int arow = tid >> 2;
  int swzc = ((tid & 3) ^ ((tid >> 3) & 3)) << 4;
  int gr0 = m0 + arow; if (gr0 > segN - 1) gr0 = segN - 1;
  const char* srcA = (const char*)x_bf + (size_t)row_token[seg0 + gr0] * 2048 + swzc;
  const char* srcB0 = (const char*)w_bf + (((size_t)e << 20) + (size_t)(n0 + arow) * 1024) * 2 + swzc;
  const char* srcB1 = srcB0 + 128 * 2048;  // +128 B-rows
  const int dA = tid * 16;
  const int dB0 = 8192 + tid * 16;
  const int dB1 = 16384 + tid * 16;

  // ---- ds_read fragment offsets (chunk = (lane>>4) ^ ((lane>>1)&3)) ----
  const int rsw = (((lane >> 4) ^ (lane >> 1)) & 3) << 4;
  int aoff[4], boff[4];
#pragma unroll
  for (int m = 0; m < 4; ++m)
    aoff[m] = (wr * 64 + m * 16 + (lane & 15)) * 64 + rsw;
#pragma unroll
  for (int n = 0; n < 4; ++n)
    boff[n] = 8192 + (wc * 64 + n * 16 + (lane & 15)) * 64 + rsw;

  f32x4 acc[4][4];
#pragma unroll
  for (int m = 0; m < 4; ++m)
#pragma unroll
    for (int n = 0; n < 4; ++n) acc[m][n] = (f32x4){0.f, 0.f, 0.f, 0.f};

  // ---- prologue: stage K-tile 0 into buf0 ----
  GLOAD16(srcA, smem + dA);
  GLOAD16(srcB0, smem + dB0);
  GLOAD16(srcB1, smem + dB1);

  // ---- main loop: 32 K-tiles, 1 barrier + 1 phase each ----
  for (int kt = 0; kt < 32; ++kt) {
    __syncthreads();  // drains vmcnt: tile kt resident in buf[kt&1]; closes reads of kt-1
    const int cur = (kt & 1) * 24576;
    const int oth = cur ^ 24576;
    bf16x8 a_[4], b_[4];
#pragma unroll
    for (int m = 0; m < 4; ++m) a_[m] = *(const bf16x8*)(smem + cur + aoff[m]);
#pragma unroll
    for (int n = 0; n < 4; ++n) b_[n] = *(const bf16x8*)(smem + cur + boff[n]);
    if (kt < 31) {
      const int kbn = (kt + 1) * 64;  // BK=32 -> 64B per row per K-tile
      GLOAD16(srcA + kbn, smem + oth + dA);
      GLOAD16(srcB0 + kbn, smem + oth + dB0);
      GLOAD16(srcB1 + kbn, smem + oth + dB1);
    }
    __builtin_amdgcn_s_setprio(1);
#pragma unroll
    for (int m = 0; m < 4; ++m)
#pragma unroll
      for (int n = 0; n < 4; ++n)
        acc[m][n] = __builtin_amdgcn_mfma_f32_16x16x32_bf16(a_[m], b_[n], acc[m][n], 0, 0, 0);
    __builtin_amdgcn_s_setprio(0);
  }

  // ---- epilogue: scale by routing weight, store bf16 ----
#pragma unroll
  for (int m = 0; m < 4; ++m) {
#pragma unroll
    for (int r = 0; r < 4; ++r) {
      int g = m0 + wr * 64 + m * 16 + ((lane >> 4) << 2) + r;
      if (g < segN) {
        int p = seg0 + g;
        float w = row_weight[p];
#pragma unroll
        for (int n = 0; n < 4; ++n) {
          int col = n0 + wc * 64 + n * 16 + (lane & 15);
          tmp[(size_t)p * 1024 + col] = f2bf(acc[m][n][r] * w);
        }
      }
    }
  }
}

// ---------------- combine: out[t] = tmp[p0] + tmp[p1] + w0*b[e0] + w1*b[e1] ----------------
__global__ __launch_bounds__(256) void combine_kernel(
    const unsigned short* __restrict__ tmp, const float* __restrict__ eb,
    const int* __restrict__ tk_e, const float* __restrict__ tk_w,
    const int* __restrict__ tk_pos, float* __restrict__ out) {
  int t = blockIdx.x;
  int o = threadIdx.x * 4;
  int p0 = tk_pos[t * 2], p1 = tk_pos[t * 2 + 1];
  int e0 = tk_e[t * 2], e1 = tk_e[t * 2 + 1];
  float w0 = tk_w[t * 2], w1 = tk_w[t * 2 + 1];
  ushort4 a = *(const ushort4*)(tmp + (size_t)p0 * 1024 + o);
  ushort4 b = *(const ushort4*)(tmp + (size_t)p1 * 1024 + o);
  float4 b0 = *(const float4*)(eb + e0 * 1024 + o);
  float4 b1 = *(const float4*)(eb + e1 * 1024 + o);
  float4 r;
  r.x = bf2f(a.x) + bf2f(b.x) + w0 * b0.x + w1 * b1.x;
  r.y = bf2f(a.y) + bf2f(b.y) + w0 * b0.y + w1 * b1.y;
  r.z = bf2f(a.z) + bf2f(b.z) + w0 * b0.z + w1 * b1.z;
  r.w = bf2f(a.w) + bf2f(b.w) + w0 * b0.w + w1 * b1.w;
  *(float4*)(out + (size_t)t * 1024 + o) = r;
}

extern "C" void kernel_launch(void* const* d_in, const int* in_sizes, int n_in,
                              void* d_out, int out_size, void* d_ws, size_t ws_size,
                              hipStream_t stream) {
  const float* x  = (const float*)d_in[0];
  const float* gw = (const float*)d_in[1];
  const float* gb = (const float*)d_in[2];
  const float* ew = (const float*)d_in[3];
  const float* eb = (const float*)d_in[4];
  float* out = (float*)d_out;
  float* logits = out + (size_t)T_TOKENS * ODIM;

  char* ws = (char*)d_ws;
  unsigned short* x_bf = (unsigned short*)(ws);                 // 16 MB
  unsigned short* w_bf = (unsigned short*)(ws + 16777216);      // 16 MB
  unsigned short* tmp  = (unsigned short*)(ws + 33554432);      // 32 MB
  int*   tk_e      = (int*)(ws + 67108864);
  float* tk_w      = (float*)(ws + 67174400);
  int*   tk_pos    = (int*)(ws + 67239936);
  int*   row_token = (int*)(ws + 67305472);
  float* row_weight= (float*)(ws + 67371008);
  int*   offsets   = (int*)(ws + 67436544);  // 9 ints
  int*   n_tiles   = (int*)(ws + 67436608);  // 2 ints: nb, cpx
  int*   tiles     = (int*)(ws + 67436672);  // up to 544 ints (block schedule)

  router_kernel<<<2048, 256, 0, stream>>>(x, gw, gb, logits, x_bf, tk_e, tk_w);
  sortconv_kernel<<<2049, 1024, 0, stream>>>(ew, w_bf, tk_e, tk_w, offsets, row_token,
                                             row_weight, tk_pos, tiles, n_tiles);
  gemm_kernel<<<544, 512, 0, stream>>>(x_bf, w_bf, row_token, row_weight, offsets, tiles,
                                       n_tiles, tmp);
  combine_kernel<<<8192, 256, 0, stream>>>(tmp, eb, tk_e, tk_w, tk_pos, out);
}

// Round 9
// 120.616 us; speedup vs baseline: 1.0528x; 1.0528x over previous
//
#include <hip/hip_runtime.h>
#include <hip/hip_bf16.h>
#include <stdint.h>

typedef __attribute__((ext_vector_type(8))) short bf16x8;
typedef __attribute__((ext_vector_type(4))) float f32x4;

#define T_TOKENS 8192
#define DIM 1024
#define ODIM 1024
#define NEXP 8

__device__ __forceinline__ unsigned short f2bf(float f) {
  unsigned u = __float_as_uint(f);
  u = (u + 0x7FFFu + ((u >> 16) & 1u)) >> 16;
  return (unsigned short)u;
}
__device__ __forceinline__ float bf2f(unsigned short h) {
  return __uint_as_float(((unsigned)h) << 16);
}

// ---------------- router: fp32 logits, top-2, weights; emits x in bf16. NO atomics. ----------------
__global__ __launch_bounds__(256) void router_kernel(
    const float* __restrict__ x, const float* __restrict__ gw, const float* __restrict__ gb,
    float* __restrict__ logits_out, unsigned short* __restrict__ x_bf,
    int* __restrict__ tk_e, float* __restrict__ tk_w) {
  int wave = threadIdx.x >> 6, lane = threadIdx.x & 63;
  int t = blockIdx.x * 4 + wave;
  float acc[NEXP];
#pragma unroll
  for (int e = 0; e < NEXP; ++e) acc[e] = 0.f;
  const float4* xr = (const float4*)(x + (size_t)t * DIM);
  ushort4* xw = (ushort4*)(x_bf + (size_t)t * DIM);
#pragma unroll
  for (int it = 0; it < 4; ++it) {
    int d4 = it * 64 + lane;
    float4 xv = xr[d4];
    ushort4 xb;
    xb.x = f2bf(xv.x); xb.y = f2bf(xv.y); xb.z = f2bf(xv.z); xb.w = f2bf(xv.w);
    xw[d4] = xb;
#pragma unroll
    for (int e = 0; e < NEXP; ++e) {
      float4 gv = ((const float4*)(gw + e * DIM))[d4];
      acc[e] += xv.x * gv.x + xv.y * gv.y + xv.z * gv.z + xv.w * gv.w;
    }
  }
#pragma unroll
  for (int off = 32; off; off >>= 1)
#pragma unroll
    for (int e = 0; e < NEXP; ++e) acc[e] += __shfl_xor(acc[e], off);
  if (lane == 0) {
#pragma unroll
    for (int e = 0; e < NEXP; ++e) acc[e] += gb[e];
    float4 lo = make_float4(acc[0], acc[1], acc[2], acc[3]);
    float4 hi = make_float4(acc[4], acc[5], acc[6], acc[7]);
    float4* lp = (float4*)(logits_out + (size_t)t * NEXP);
    lp[0] = lo; lp[1] = hi;
    int e0 = 0; float l0 = acc[0];
#pragma unroll
    for (int e = 1; e < NEXP; ++e) if (acc[e] > l0) { l0 = acc[e]; e0 = e; }
    int e1 = -1; float l1 = -1e30f;
#pragma unroll
    for (int e = 0; e < NEXP; ++e) if (e != e0 && acc[e] > l1) { l1 = acc[e]; e1 = e; }
    float r = expf(l1 - l0);          // p1/p0
    float w0 = 1.f / (1.f + r);
    float w1 = r * w0;
    tk_e[t * 2] = e0; tk_e[t * 2 + 1] = e1;
    tk_w[t * 2] = w0; tk_w[t * 2 + 1] = w1;
  }
}

// ---------------- fused: block 0 = counting sort + tile schedule; blocks 1..2048 = expert_w convert.
__global__ __launch_bounds__(1024) void sortconv_kernel(
    const float* __restrict__ ew, unsigned short* __restrict__ w_bf,
    const int* __restrict__ tk_e, const float* __restrict__ tk_w,
    int* __restrict__ offsets_g, int* __restrict__ row_token,
    float* __restrict__ row_weight, int* __restrict__ tk_pos,
    int* __restrict__ tiles_g, int* __restrict__ n_tiles_g) {
  if (blockIdx.x > 0) {
    int i = (blockIdx.x - 1) * 1024 + threadIdx.x;  // 2M float4s
    float4 v = ((const float4*)ew)[i];
    ushort4 o;
    o.x = f2bf(v.x); o.y = f2bf(v.y); o.z = f2bf(v.z); o.w = f2bf(v.w);
    ((ushort4*)w_bf)[i] = o;
    return;
  }
  int tid = threadIdx.x;
  int lane = tid & 63, wv = tid >> 6;  // 16 waves
  __shared__ int wavetot[16][NEXP];    // then reused as wave exclusive base
  __shared__ int offs_l[NEXP + 1];

  int pe[16];
  float tw[16];
  const int base = tid * 16;
#pragma unroll
  for (int i = 0; i < 4; ++i) {
    int4 v = ((const int4*)(tk_e + base))[i];
    pe[i * 4 + 0] = v.x; pe[i * 4 + 1] = v.y; pe[i * 4 + 2] = v.z; pe[i * 4 + 3] = v.w;
    float4 w = ((const float4*)(tk_w + base))[i];
    tw[i * 4 + 0] = w.x; tw[i * 4 + 1] = w.y; tw[i * 4 + 2] = w.z; tw[i * 4 + 3] = w.w;
  }
  int h[NEXP];
#pragma unroll
  for (int e = 0; e < NEXP; ++e) h[e] = 0;
#pragma unroll
  for (int i = 0; i < 16; ++i)
#pragma unroll
    for (int e = 0; e < NEXP; ++e) h[e] += (pe[i] == e);

  int incl[NEXP];
#pragma unroll
  for (int e = 0; e < NEXP; ++e) incl[e] = h[e];
#pragma unroll
  for (int off = 1; off < 64; off <<= 1) {
#pragma unroll
    for (int e = 0; e < NEXP; ++e) {
      int n = __shfl_up(incl[e], off);
      if (lane >= off) incl[e] += n;
    }
  }
  if (lane == 63)
#pragma unroll
    for (int e = 0; e < NEXP; ++e) wavetot[wv][e] = incl[e];
  __syncthreads();
  if (tid == 0) {
    int tot[NEXP];
#pragma unroll
    for (int e = 0; e < NEXP; ++e) tot[e] = 0;
    for (int w = 0; w < 16; ++w)
#pragma unroll
      for (int e = 0; e < NEXP; ++e) {
        int v = wavetot[w][e];
        wavetot[w][e] = tot[e];  // exclusive base per wave
        tot[e] += v;
      }
    int o = 0;
#pragma unroll
    for (int e = 0; e < NEXP; ++e) { offs_l[e] = o; o += tot[e]; }
    offs_l[NEXP] = o;
    for (int e = 0; e <= NEXP; ++e) offsets_g[e] = offs_l[e];
    // block schedule: expert-major, m-tile(128 rows) major, n-tile(256 cols) fast
    int nb = 0;
    for (int e = 0; e < NEXP; ++e) {
      int mt = (tot[e] + 127) >> 7;
      for (int m = 0; m < mt; ++m)
        for (int n = 0; n < 4; ++n) tiles_g[nb++] = e | (n << 4) | (m << 8);
    }
    n_tiles_g[0] = nb;
    n_tiles_g[1] = (nb + 7) >> 3;  // chunk size per XCD column
  }
  __syncthreads();

  int mybase[NEXP];
#pragma unroll
  for (int e = 0; e < NEXP; ++e) mybase[e] = offs_l[e] + wavetot[wv][e] + (incl[e] - h[e]);
  int run[NEXP];
#pragma unroll
  for (int e = 0; e < NEXP; ++e) run[e] = 0;
#pragma unroll
  for (int i = 0; i < 16; ++i) {
    int pos = 0;
#pragma unroll
    for (int e = 0; e < NEXP; ++e)
      if (pe[i] == e) { pos = mybase[e] + run[e]; run[e]++; }
    int pair = base + i;
    row_token[pos] = pair >> 1;
    row_weight[pos] = tw[i];
    tk_pos[pair] = pos;
  }
}

// ---------------- grouped GEMM: 128x256 tile, BK=32, TRIPLE-buffered LDS (3x24KB=72KB, 2 blocks/CU),
// counted s_waitcnt vmcnt(3) per K-tile (never drains to 0 mid-loop), 1 barrier/K-tile.
#define GLOAD16(g, l)                                                                   \
  __builtin_amdgcn_global_load_lds((const __attribute__((address_space(1))) unsigned int*)(g), \
                                   (__attribute__((address_space(3))) unsigned int*)(l), 16, 0, 0)
#define BUFSZ 24576

__global__ __launch_bounds__(512, 4) void gemm_kernel(
    const unsigned short* __restrict__ x_bf, const unsigned short* __restrict__ w_bf,
    const int* __restrict__ row_token, const float* __restrict__ row_weight,
    const int* __restrict__ offsets, const int* __restrict__ tiles,
    const int* __restrict__ n_tiles, unsigned short* __restrict__ tmp) {
  int nb = n_tiles[0], cpx = n_tiles[1];
  int wg = blockIdx.x;
  int slot = wg >> 3;
  if (slot >= cpx) return;
  int idx = (wg & 7) * cpx + slot;   // chunked: XCD column gets contiguous schedule run
  if (idx >= nb) return;
  int s = tiles[idx];
  int e = s & 7;
  int n0 = ((s >> 4) & 3) << 8;
  int m0 = (s >> 8) << 7;
  int seg0 = offsets[e], segN = offsets[e + 1] - seg0;

  int tid = threadIdx.x;
  int lane = tid & 63, wave = tid >> 6;
  int wr = wave >> 2, wc = wave & 3;  // 2M x 4N wave grid; wave output 64x64

  // per buffer (24KB): A[128][32]bf16 @0 (8KB), B[256][32]bf16 @8192. 3 buffers.
  __shared__ __align__(16) char smem[3 * BUFSZ];

  // ---- staging: per K-tile 3 gloads (1 A + 2 B), each 512thr x 16B. 64B rows,
  // chunk swizzle: chunk ^= (row>>1)&3 (conflict-free per 8-lane subgroup). ----
  int arow = tid >> 2;
  int swzc = ((tid & 3) ^ ((tid >> 3) & 3)) << 4;
  int gr0 = m0 + arow; if (gr0 > segN - 1) gr0 = segN - 1;
  const char* srcA = (const char*)x_bf + (size_t)row_token[seg0 + gr0] * 2048 + swzc;
  const char* srcB0 = (const char*)w_bf + (((size_t)e << 20) + (size_t)(n0 + arow) * 1024) * 2 + swzc;
  const char* srcB1 = srcB0 + 128 * 2048;  // +128 B-rows
  const int dA = tid * 16;
  const int dB0 = 8192 + tid * 16;
  const int dB1 = 16384 + tid * 16;

  // ---- ds_read fragment offsets (chunk = (lane>>4) ^ ((lane>>1)&3)) ----
  const int rsw = (((lane >> 4) ^ (lane >> 1)) & 3) << 4;
  int aoff[4], boff[4];
#pragma unroll
  for (int m = 0; m < 4; ++m)
    aoff[m] = (wr * 64 + m * 16 + (lane & 15)) * 64 + rsw;
#pragma unroll
  for (int n = 0; n < 4; ++n)
    boff[n] = 8192 + (wc * 64 + n * 16 + (lane & 15)) * 64 + rsw;

  f32x4 acc[4][4];
#pragma unroll
  for (int m = 0; m < 4; ++m)
#pragma unroll
    for (int n = 0; n < 4; ++n) acc[m][n] = (f32x4){0.f, 0.f, 0.f, 0.f};

#define STAGE3(bufo, kb)                           \
  {                                                \
    GLOAD16(srcA + (kb), smem + (bufo) + dA);      \
    GLOAD16(srcB0 + (kb), smem + (bufo) + dB0);    \
    GLOAD16(srcB1 + (kb), smem + (bufo) + dB1);    \
  }

  // ---- prologue: stage K-tiles 0,1 into buf0,buf1 (6 loads in flight) ----
  STAGE3(0, 0);
  STAGE3(BUFSZ, 64);

  // ---- main loop: 32 K-tiles; counted vmcnt, ONE barrier per K-tile ----
  int cb = 0;
  for (int kt = 0; kt < 32; ++kt) {
    // retire tile kt's 3 loads; keep tile kt+1's 3 in flight (except last iter).
    if (kt < 31) {
      asm volatile("s_waitcnt vmcnt(3)" ::: "memory");
    } else {
      asm volatile("s_waitcnt vmcnt(0)" ::: "memory");
    }
    __builtin_amdgcn_s_barrier();
    const int cur = cb * BUFSZ;
    bf16x8 a_[4], b_[4];
#pragma unroll
    for (int m = 0; m < 4; ++m) a_[m] = *(const bf16x8*)(smem + cur + aoff[m]);
#pragma unroll
    for (int n = 0; n < 4; ++n) b_[n] = *(const bf16x8*)(smem + cur + boff[n]);
    if (kt < 30) {
      int cbn = cb + 2; if (cbn >= 3) cbn -= 3;   // buffer for tile kt+2
      const int kbn = (kt + 2) * 64;              // BK=32 -> 64B per row per K-tile
      STAGE3(cbn * BUFSZ, kbn);
    }
    __builtin_amdgcn_s_setprio(1);
#pragma unroll
    for (int m = 0; m < 4; ++m)
#pragma unroll
      for (int n = 0; n < 4; ++n)
        acc[m][n] = __builtin_amdgcn_mfma_f32_16x16x32_bf16(a_[m], b_[n], acc[m][n], 0, 0, 0);
    __builtin_amdgcn_s_setprio(0);
    cb = (cb + 1 == 3) ? 0 : cb + 1;
  }

  // ---- epilogue: scale by routing weight, store bf16 ----
#pragma unroll
  for (int m = 0; m < 4; ++m) {
#pragma unroll
    for (int r = 0; r < 4; ++r) {
      int g = m0 + wr * 64 + m * 16 + ((lane >> 4) << 2) + r;
      if (g < segN) {
        int p = seg0 + g;
        float w = row_weight[p];
#pragma unroll
        for (int n = 0; n < 4; ++n) {
          int col = n0 + wc * 64 + n * 16 + (lane & 15);
          tmp[(size_t)p * 1024 + col] = f2bf(acc[m][n][r] * w);
        }
      }
    }
  }
#undef STAGE3
}

// ---------------- combine: out[t] = tmp[p0] + tmp[p1] + w0*b[e0] + w1*b[e1] ----------------
__global__ __launch_bounds__(256) void combine_kernel(
    const unsigned short* __restrict__ tmp, const float* __restrict__ eb,
    const int* __restrict__ tk_e, const float* __restrict__ tk_w,
    const int* __restrict__ tk_pos, float* __restrict__ out) {
  int t = blockIdx.x;
  int o = threadIdx.x * 4;
  int p0 = tk_pos[t * 2], p1 = tk_pos[t * 2 + 1];
  int e0 = tk_e[t * 2], e1 = tk_e[t * 2 + 1];
  float w0 = tk_w[t * 2], w1 = tk_w[t * 2 + 1];
  ushort4 a = *(const ushort4*)(tmp + (size_t)p0 * 1024 + o);
  ushort4 b = *(const ushort4*)(tmp + (size_t)p1 * 1024 + o);
  float4 b0 = *(const float4*)(eb + e0 * 1024 + o);
  float4 b1 = *(const float4*)(eb + e1 * 1024 + o);
  float4 r;
  r.x = bf2f(a.x) + bf2f(b.x) + w0 * b0.x + w1 * b1.x;
  r.y = bf2f(a.y) + bf2f(b.y) + w0 * b0.y + w1 * b1.y;
  r.z = bf2f(a.z) + bf2f(b.z) + w0 * b0.z + w1 * b1.z;
  r.w = bf2f(a.w) + bf2f(b.w) + w0 * b0.w + w1 * b1.w;
  *(float4*)(out + (size_t)t * 1024 + o) = r;
}

extern "C" void kernel_launch(void* const* d_in, const int* in_sizes, int n_in,
                              void* d_out, int out_size, void* d_ws, size_t ws_size,
                              hipStream_t stream) {
  const float* x  = (const float*)d_in[0];
  const float* gw = (const float*)d_in[1];
  const float* gb = (const float*)d_in[2];
  const float* ew = (const float*)d_in[3];
  const float* eb = (const float*)d_in[4];
  float* out = (float*)d_out;
  float* logits = out + (size_t)T_TOKENS * ODIM;

  char* ws = (char*)d_ws;
  unsigned short* x_bf = (unsigned short*)(ws);                 // 16 MB
  unsigned short* w_bf = (unsigned short*)(ws + 16777216);      // 16 MB
  unsigned short* tmp  = (unsigned short*)(ws + 33554432);      // 32 MB
  int*   tk_e      = (int*)(ws + 67108864);
  float* tk_w      = (float*)(ws + 67174400);
  int*   tk_pos    = (int*)(ws + 67239936);
  int*   row_token = (int*)(ws + 67305472);
  float* row_weight= (float*)(ws + 67371008);
  int*   offsets   = (int*)(ws + 67436544);  // 9 ints
  int*   n_tiles   = (int*)(ws + 67436608);  // 2 ints: nb, cpx
  int*   tiles     = (int*)(ws + 67436672);  // up to 544 ints (block schedule)

  router_kernel<<<2048, 256, 0, stream>>>(x, gw, gb, logits, x_bf, tk_e, tk_w);
  sortconv_kernel<<<2049, 1024, 0, stream>>>(ew, w_bf, tk_e, tk_w, offsets, row_token,
                                             row_weight, tk_pos, tiles, n_tiles);
  gemm_kernel<<<544, 512, 0, stream>>>(x_bf, w_bf, row_token, row_weight, offsets, tiles,
                                       n_tiles, tmp);
  combine_kernel<<<8192, 256, 0, stream>>>(tmp, eb, tk_e, tk_w, tk_pos, out);
}